// Round 4
// baseline (442.488 us; speedup 1.0000x reference)
//
#include <hip/hip_runtime.h>

#define N_NODES 100000
#define N_EDGES 1250000
#define D 64

#define BSHIFT 9
#define BUCKETS 196          // ceil(100000 / 512)
#define CAP 8192             // srtTmp capacity per bucket (mean 6378, +22 sigma)
#define CHUNK 4096           // edges per bucketA block
#define PA_BLOCKS ((N_EDGES + CHUNK - 1) / CHUNK)   // 306
#define LCAP 64              // LDS list capacity per bucket per chunk (mean 21, max<64)

typedef long long ll;
typedef unsigned int uint;

// round-to-nearest-even fp32 -> bf16
__device__ __forceinline__ ushort f2bf(float f) {
    uint u = __float_as_uint(f);
    u += 0x7fffu + ((u >> 16) & 1u);
    return (ushort)(u >> 16);
}

// ---------- init: cursor[b] = b*CAP; zero-pad srt tail; offs[N] sentinel ----------
__global__ void init_kernel(int* __restrict__ cursor, int* __restrict__ srt,
                            int* __restrict__ offs) {
    int t = threadIdx.x;
    if (t < BUCKETS) cursor[t] = t * CAP;
    if (t < 8) srt[N_EDGES + t] = 0;
    if (t == 0) offs[N_NODES] = N_EDGES;
}

// ---------- pass A: bin edges into 196 coarse buckets ----------
// 512 threads; flush is two parallel phases: (1) 196 concurrent cursor atomics,
// (2) one coalesced 64-lane store per bucket (no serial per-thread copy loop).
__global__ __launch_bounds__(512) void bucketA_kernel(const int* __restrict__ src,
                                                      const int* __restrict__ dst,
                                                      int* __restrict__ cursor,
                                                      int* __restrict__ tmp) {
    __shared__ int lcnt[BUCKETS];
    __shared__ int gbs[BUCKETS];
    __shared__ int list[BUCKETS * LCAP];   // ~49 KB
    int tid = threadIdx.x;
    if (tid < BUCKETS) lcnt[tid] = 0;
    __syncthreads();

    int base = blockIdx.x * CHUNK;
    int nE = min(CHUNK, N_EDGES - base);
    for (int i = tid; i < nE; i += 512) {
        int e = base + i;
        int s = src[e], d = dst[e];
        int b = d >> BSHIFT;
        int p = atomicAdd(&lcnt[b], 1);            // LDS atomic, cheap
        list[b * LCAP + p] = s | ((d & 511) << 17); // src:17b, dstLow:9b
    }
    __syncthreads();

    if (tid < BUCKETS) gbs[tid] = atomicAdd(&cursor[tid], lcnt[tid]);  // parallel
    __syncthreads();

    int wv = tid >> 6, lane = tid & 63;
    for (int b = wv; b < BUCKETS; b += 8) {        // 8 waves, fire-and-forget stores
        int c = lcnt[b];
        if (lane < c) tmp[gbs[b] + lane] = list[b * LCAP + lane];
    }
}

// ---------- pass B: per-bucket local sort -> final srt + offs ----------
// Absorbs the global scan: every block recomputes the tiny 196-entry prefix sum.
__global__ __launch_bounds__(512) void bucketB_kernel(const int* __restrict__ cursor,
                                                      const int* __restrict__ tmp,
                                                      int* __restrict__ srt,
                                                      int* __restrict__ offs) {
    __shared__ int hist[512];
    __shared__ int s[512];
    __shared__ int cur[512];
    int b = blockIdx.x, tid = threadIdx.x;
    int cbase = b * CAP;
    int cnt = cursor[b] - cbase;

    // --- inline exclusive scan over 196 bucket counts (uses s[0..255]) ---
    if (tid < 256) s[tid] = (tid < BUCKETS) ? (cursor[tid] - tid * CAP) : 0;
    __syncthreads();
    for (int off = 1; off < 256; off <<= 1) {
        int v = (tid >= off && tid < 256) ? s[tid - off] : 0;
        __syncthreads();
        if (tid < 256) s[tid] += v;
        __syncthreads();
    }
    const int gbase = s[b] - cnt;       // exclusive prefix at own bucket
    __syncthreads();                    // before s[] is reused below

    hist[tid] = 0;
    __syncthreads();
    for (int i = tid; i < cnt; i += 512) {
        int ln = tmp[cbase + i] >> 17;
        atomicAdd(&hist[ln], 1);        // LDS atomic, avg 12.5/node
    }
    __syncthreads();

    // inclusive Hillis-Steele over 512 -> exclusive
    int x = hist[tid];
    s[tid] = x;
    __syncthreads();
    for (int off = 1; off < 512; off <<= 1) {
        int v = (tid >= off) ? s[tid - off] : 0;
        __syncthreads();
        s[tid] += v;
        __syncthreads();
    }
    int excl = s[tid] - x;
    cur[tid] = excl;

    int node0 = b << BSHIFT;
    int nloc = min(512, N_NODES - node0);
    if (tid < nloc) offs[node0 + tid] = gbase + excl;   // coalesced
    __syncthreads();

    for (int i = tid; i < cnt; i += 512) {
        int v = tmp[cbase + i];            // L2-hot (second read)
        int ln = v >> 17;
        int p = atomicAdd(&cur[ln], 1);
        srt[gbase + p] = v & 0x1FFFF;      // random within 25KB window, L2-buffered
    }
}

// ---------- fp32 -> bf16 bulk convert (x -> xb, done once) ----------
__global__ __launch_bounds__(256) void cvt_kernel(const float* __restrict__ x,
                                                  ushort* __restrict__ xb) {
    const int n4 = N_NODES * D / 4;
    int i = blockIdx.x * 256 + threadIdx.x;
    const int stride = gridDim.x * 256;
    for (; i < n4; i += stride) {
        float4 v = ((const float4*)x)[i];
        ushort4 o;
        o.x = f2bf(v.x); o.y = f2bf(v.y); o.z = f2bf(v.z); o.w = f2bf(v.w);
        ((ushort4*)xb)[i] = o;
    }
}

// ---------- fused pull + linear: bf16 gather, node-pair, 8 loads in flight ----------
// R2 structure (the best measured: 70.8us/layer) + forced 8 waves/EU occupancy.
// Each wave owns node pair (2p, 2p+1). sub = lane&15 covers the 64-dim bf16 row
// as uint2 (8B = 4 bf16); g = lane>>4 is the edge slot. Both nodes' 16-edge
// batches issue before any wait -> 8 row-gathers outstanding per wave; with
// VGPR<=64 the CU holds 32 waves -> 256 requests/CU in flight.
#define NBLK 2048
#define ACC4(P, M, AX, AY, AZ, AW)                        \
    {                                                     \
        float f0 = __uint_as_float((P).x << 16);          \
        float f1 = __uint_as_float((P).x & 0xffff0000u);  \
        float f2 = __uint_as_float((P).y << 16);          \
        float f3 = __uint_as_float((P).y & 0xffff0000u);  \
        AX = fmaf(f0, (M), AX); AY = fmaf(f1, (M), AY);   \
        AZ = fmaf(f2, (M), AZ); AW = fmaf(f3, (M), AW);   \
    }

template<int EMIT>
__global__ __launch_bounds__(256, 8) void fused_layer(const ushort* __restrict__ hb,
                                                      const int* __restrict__ offs,
                                                      const int* __restrict__ srt,
                                                      const float* __restrict__ W1,
                                                      const float* __restrict__ b1,
                                                      float* __restrict__ out,
                                                      ushort* __restrict__ outb) {
    __shared__ __align__(16) float rbA[4][64];
    __shared__ __align__(16) float rbB[4][64];
    const int tid  = threadIdx.x;
    const int lane = tid & 63;
    const int wid  = tid >> 6;
    const int g    = lane >> 4;      // edge slot group 0..3
    const int sub  = lane & 15;      // uint2 (4 bf16) within the row
    const int gw   = blockIdx.x * 4 + wid;
    const int GW   = NBLK * 4;
    const int goff = g << 2;

    const float4* wrow = (const float4*)(W1 + lane * D);
    const float bj = b1[lane];

    for (int p = gw; p < (N_NODES >> 1); p += GW) {
        const int nA = p << 1;
        const int2 o2 = *(const int2*)(offs + nA);   // begA, endA(=begB)
        const int begA = o2.x;
        const int endA = o2.y;
        const int endB = offs[nA + 2];               // offs[N] sentinel = N_EDGES
        const int emA = (endA > begA) ? endA - 1 : begA;  // deg-0 safe (srt zero-padded)
        const int emB = (endB > endA) ? endB - 1 : endA;

        float aAx = 0.f, aAy = 0.f, aAz = 0.f, aAw = 0.f;
        float aBx = 0.f, aBy = 0.f, aBz = 0.f, aBw = 0.f;

        int ebA = begA, ebB = endA;
        while (ebA < endA || ebB < endB) {
            const int eA = ebA + goff;
            const int eB = ebB + goff;
            const int cA0 = min(eA,     emA), cA1 = min(eA + 1, emA);
            const int cA2 = min(eA + 2, emA), cA3 = min(eA + 3, emA);
            const int cB0 = min(eB,     emB), cB1 = min(eB + 1, emB);
            const int cB2 = min(eB + 2, emB), cB3 = min(eB + 3, emB);
            const int sA0 = srt[cA0];
            const int sA1 = srt[cA1];
            const int sA2 = srt[cA2];
            const int sA3 = srt[cA3];
            const int sB0 = srt[cB0];
            const int sB1 = srt[cB1];
            const int sB2 = srt[cB2];
            const int sB3 = srt[cB3];
            const uint2 vA0 = *((const uint2*)(hb + (ll)sA0 * D) + sub);
            const uint2 vA1 = *((const uint2*)(hb + (ll)sA1 * D) + sub);
            const uint2 vA2 = *((const uint2*)(hb + (ll)sA2 * D) + sub);
            const uint2 vA3 = *((const uint2*)(hb + (ll)sA3 * D) + sub);
            const uint2 vB0 = *((const uint2*)(hb + (ll)sB0 * D) + sub);
            const uint2 vB1 = *((const uint2*)(hb + (ll)sB1 * D) + sub);
            const uint2 vB2 = *((const uint2*)(hb + (ll)sB2 * D) + sub);
            const uint2 vB3 = *((const uint2*)(hb + (ll)sB3 * D) + sub);
            const float mA0 = (eA     < endA) ? 1.f : 0.f;
            const float mA1 = (eA + 1 < endA) ? 1.f : 0.f;
            const float mA2 = (eA + 2 < endA) ? 1.f : 0.f;
            const float mA3 = (eA + 3 < endA) ? 1.f : 0.f;
            const float mB0 = (eB     < endB) ? 1.f : 0.f;
            const float mB1 = (eB + 1 < endB) ? 1.f : 0.f;
            const float mB2 = (eB + 2 < endB) ? 1.f : 0.f;
            const float mB3 = (eB + 3 < endB) ? 1.f : 0.f;
            ACC4(vA0, mA0, aAx, aAy, aAz, aAw);
            ACC4(vA1, mA1, aAx, aAy, aAz, aAw);
            ACC4(vA2, mA2, aAx, aAy, aAz, aAw);
            ACC4(vA3, mA3, aAx, aAy, aAz, aAw);
            ACC4(vB0, mB0, aBx, aBy, aBz, aBw);
            ACC4(vB1, mB1, aBx, aBy, aBz, aBw);
            ACC4(vB2, mB2, aBx, aBy, aBz, aBw);
            ACC4(vB3, mB3, aBx, aBy, aBz, aBw);
            ebA += 16; ebB += 16;
        }

        // cross-group reduce: after xor16+xor32 every lane holds the full sum
        aAx += __shfl_xor(aAx, 16); aAy += __shfl_xor(aAy, 16);
        aAz += __shfl_xor(aAz, 16); aAw += __shfl_xor(aAw, 16);
        aBx += __shfl_xor(aBx, 16); aBy += __shfl_xor(aBy, 16);
        aBz += __shfl_xor(aBz, 16); aBw += __shfl_xor(aBw, 16);
        aAx += __shfl_xor(aAx, 32); aAy += __shfl_xor(aAy, 32);
        aAz += __shfl_xor(aAz, 32); aAw += __shfl_xor(aAw, 32);
        aBx += __shfl_xor(aBx, 32); aBy += __shfl_xor(aBy, 32);
        aBz += __shfl_xor(aBz, 32); aBw += __shfl_xor(aBw, 32);

        if (g == 0) {
            float4 t; t.x = aAx; t.y = aAy; t.z = aAz; t.w = aAw;
            *((float4*)rbA[wid] + sub) = t;     // wave-internal, in-order DS pipe
        }
        if (g == 1) {
            float4 t; t.x = aBx; t.y = aBy; t.z = aBz; t.w = aBw;
            *((float4*)rbB[wid] + sub) = t;
        }

        float oA = bj, oB = bj;
        const float4* ra = (const float4*)rbA[wid];
        const float4* rb = (const float4*)rbB[wid];
#pragma unroll
        for (int k4 = 0; k4 < 16; ++k4) {
            const float4 w = wrow[k4];           // L1-resident (16KB), per-lane row
            const float4 rA = ra[k4];            // LDS broadcast, conflict-free
            const float4 rB = rb[k4];
            oA += rA.x * w.x + rA.y * w.y + rA.z * w.z + rA.w * w.w;
            oB += rB.x * w.x + rB.y * w.y + rB.z * w.z + rB.w * w.w;
        }
        __builtin_nontemporal_store(oA, out + (ll)nA * D + lane);
        __builtin_nontemporal_store(oB, out + (ll)(nA + 1) * D + lane);
        if (EMIT) {
            outb[(ll)nA * D + lane]       = f2bf(oA);   // plain store: keep L2-hot
            outb[(ll)(nA + 1) * D + lane] = f2bf(oB);
        }
    }
}

extern "C" void kernel_launch(void* const* d_in, const int* in_sizes, int n_in,
                              void* d_out, int out_size, void* d_ws, size_t ws_size,
                              hipStream_t stream) {
    const float* x  = (const float*)d_in[0];   // [N, D]
    const int* edge = (const int*)d_in[1];     // [2, E]: src row then dst row
    const float* W1 = (const float*)d_in[2];   // [D, D]
    const float* b1 = (const float*)d_in[3];   // [D]

    const int* src = edge;
    const int* dst = edge + N_EDGES;

    float* out = (float*)d_out;                    // output 0: [N, D]
    float* hid = (float*)d_out + (ll)N_NODES * D;  // output 1: [N, D]

    // xb (bf16 copy of x) lives in the `out` region of d_out: it is only read
    // during layer 1 (which writes hid), and layer 2 overwrites every element.
    ushort* xb = (ushort*)d_out;

    // workspace layout (~24.7 MiB; 25.6 MB proven available)
    char* ws = (char*)d_ws;
    int* cursor   = (int*)ws;  ws += 1024;                                       // [196]
    int* offs     = (int*)ws;  ws += ((size_t)(N_NODES + 1) * 4 + 255) & ~255ull;// [N+1]
    int* srt      = (int*)ws;  ws += ((size_t)(N_EDGES + 8) * 4 + 255) & ~255ull;// [E+8]
    ushort* hidb  = (ushort*)ws; ws += (size_t)N_NODES * D * 2;                  // [N,D] bf16
    int* tmp      = (int*)ws;                                                    // [196*CAP]

    // ---- build CSR via two-pass bucket sort (once; reused by both layers) ----
    init_kernel<<<1, 256, 0, stream>>>(cursor, srt, offs);
    bucketA_kernel<<<PA_BLOCKS, 512, 0, stream>>>(src, dst, cursor, tmp);
    bucketB_kernel<<<BUCKETS, 512, 0, stream>>>(cursor, tmp, srt, offs);

    // ---- bf16 copy of x ----
    cvt_kernel<<<2048, 256, 0, stream>>>(x, xb);

    // ---- layer 1: hid = segsum(x) @ W1^T + b1 (bf16 gather; emits bf16 hid) ----
    fused_layer<1><<<NBLK, 256, 0, stream>>>(xb, offs, srt, W1, b1, hid, hidb);
    // ---- layer 2: out = segsum(hid) @ W1^T + b1 (bf16 gather) ----
    fused_layer<0><<<NBLK, 256, 0, stream>>>(hidb, offs, srt, W1, b1, out, (ushort*)nullptr);
}

// Round 5
// 247.406 us; speedup vs baseline: 1.7885x; 1.7885x over previous
//
#include <hip/hip_runtime.h>

#define N_NODES 100000
#define N_EDGES 1250000
#define D 64

#define BSHIFT 9
#define BUCKETS 196          // ceil(100000 / 512)
#define CAP 8192             // srtTmp capacity per bucket (mean 6378, +22 sigma)
#define CHUNK 4096           // edges per bucketA block
#define PA_BLOCKS ((N_EDGES + CHUNK - 1) / CHUNK)   // 306
#define LCAP 64              // LDS list capacity per bucket per chunk (mean 21, max<64)

typedef long long ll;
typedef unsigned int uint;

// round-to-nearest-even fp32 -> bf16
__device__ __forceinline__ ushort f2bf(float f) {
    uint u = __float_as_uint(f);
    u += 0x7fffu + ((u >> 16) & 1u);
    return (ushort)(u >> 16);
}

// ---------- init: cursor[b] = b*CAP; zero-pad srt tail; offs[N] sentinel ----------
__global__ void init_kernel(int* __restrict__ cursor, int* __restrict__ srt,
                            int* __restrict__ offs) {
    int t = threadIdx.x;
    if (t < BUCKETS) cursor[t] = t * CAP;
    if (t < 8) srt[N_EDGES + t] = 0;
    if (t == 0) offs[N_NODES] = N_EDGES;
}

// ---------- pass A: bin edges into 196 coarse buckets ----------
// 512 threads; flush is two parallel phases: (1) 196 concurrent cursor atomics,
// (2) one coalesced 64-lane store per bucket (no serial per-thread copy loop).
__global__ __launch_bounds__(512) void bucketA_kernel(const int* __restrict__ src,
                                                      const int* __restrict__ dst,
                                                      int* __restrict__ cursor,
                                                      int* __restrict__ tmp) {
    __shared__ int lcnt[BUCKETS];
    __shared__ int gbs[BUCKETS];
    __shared__ int list[BUCKETS * LCAP];   // ~49 KB
    int tid = threadIdx.x;
    if (tid < BUCKETS) lcnt[tid] = 0;
    __syncthreads();

    int base = blockIdx.x * CHUNK;
    int nE = min(CHUNK, N_EDGES - base);
    for (int i = tid; i < nE; i += 512) {
        int e = base + i;
        int s = src[e], d = dst[e];
        int b = d >> BSHIFT;
        int p = atomicAdd(&lcnt[b], 1);            // LDS atomic, cheap
        list[b * LCAP + p] = s | ((d & 511) << 17); // src:17b, dstLow:9b
    }
    __syncthreads();

    if (tid < BUCKETS) gbs[tid] = atomicAdd(&cursor[tid], lcnt[tid]);  // parallel
    __syncthreads();

    int wv = tid >> 6, lane = tid & 63;
    for (int b = wv; b < BUCKETS; b += 8) {        // 8 waves, fire-and-forget stores
        int c = lcnt[b];
        if (lane < c) tmp[gbs[b] + lane] = list[b * LCAP + lane];
    }
}

// ---------- pass B: per-bucket local sort -> final srt + offs ----------
// Absorbs the global scan: every block recomputes the tiny 196-entry prefix sum.
__global__ __launch_bounds__(512) void bucketB_kernel(const int* __restrict__ cursor,
                                                      const int* __restrict__ tmp,
                                                      int* __restrict__ srt,
                                                      int* __restrict__ offs) {
    __shared__ int hist[512];
    __shared__ int s[512];
    __shared__ int cur[512];
    int b = blockIdx.x, tid = threadIdx.x;
    int cbase = b * CAP;
    int cnt = cursor[b] - cbase;

    // --- inline exclusive scan over 196 bucket counts (uses s[0..255]) ---
    if (tid < 256) s[tid] = (tid < BUCKETS) ? (cursor[tid] - tid * CAP) : 0;
    __syncthreads();
    for (int off = 1; off < 256; off <<= 1) {
        int v = (tid >= off && tid < 256) ? s[tid - off] : 0;
        __syncthreads();
        if (tid < 256) s[tid] += v;
        __syncthreads();
    }
    const int gbase = s[b] - cnt;       // exclusive prefix at own bucket
    __syncthreads();                    // before s[] is reused below

    hist[tid] = 0;
    __syncthreads();
    for (int i = tid; i < cnt; i += 512) {
        int ln = tmp[cbase + i] >> 17;
        atomicAdd(&hist[ln], 1);        // LDS atomic, avg 12.5/node
    }
    __syncthreads();

    // inclusive Hillis-Steele over 512 -> exclusive
    int x = hist[tid];
    s[tid] = x;
    __syncthreads();
    for (int off = 1; off < 512; off <<= 1) {
        int v = (tid >= off) ? s[tid - off] : 0;
        __syncthreads();
        s[tid] += v;
        __syncthreads();
    }
    int excl = s[tid] - x;
    cur[tid] = excl;

    int node0 = b << BSHIFT;
    int nloc = min(512, N_NODES - node0);
    if (tid < nloc) offs[node0 + tid] = gbase + excl;   // coalesced
    __syncthreads();

    for (int i = tid; i < cnt; i += 512) {
        int v = tmp[cbase + i];            // L2-hot (second read)
        int ln = v >> 17;
        int p = atomicAdd(&cur[ln], 1);
        srt[gbase + p] = v & 0x1FFFF;      // random within 25KB window, L2-buffered
    }
}

// ---------- fp32 -> bf16 bulk convert (x -> xb, done once) ----------
__global__ __launch_bounds__(256) void cvt_kernel(const float* __restrict__ x,
                                                  ushort* __restrict__ xb) {
    const int n4 = N_NODES * D / 4;
    int i = blockIdx.x * 256 + threadIdx.x;
    const int stride = gridDim.x * 256;
    for (; i < n4; i += stride) {
        float4 v = ((const float4*)x)[i];
        ushort4 o;
        o.x = f2bf(v.x); o.y = f2bf(v.y); o.z = f2bf(v.z); o.w = f2bf(v.w);
        ((ushort4*)xb)[i] = o;
    }
}

// ---------- fused pull + linear: uint4 bf16 gather, node-pair ----------
// Lane layout: g8 = lane>>3 is the edge slot (8 slots/instruction), sub8 = lane&7
// covers the 128-B bf16 row as uint4 (16 B/lane = coalescing sweet spot).
// Per iteration each node gets a 16-edge batch = 2 idx loads + 2 gathers
// -> 8 VMEM in flight per wave at HALF R2's instruction count per edge.
// 32-bit saddr offsets keep the live set ~52 VGPR (under the 64-reg occupancy
// cliff -> 8 waves/SIMD cap). NO min-waves launch bound (R4: forcing -> spills).
// Tail slots clamp to a valid index (L1-hit dup) and are masked via fmaf.
#define NBLK 2048

__device__ __forceinline__ void uacc(const uint4 v, float m, float* a) {
    a[0] = fmaf(__uint_as_float(v.x << 16),         m, a[0]);
    a[1] = fmaf(__uint_as_float(v.x & 0xffff0000u), m, a[1]);
    a[2] = fmaf(__uint_as_float(v.y << 16),         m, a[2]);
    a[3] = fmaf(__uint_as_float(v.y & 0xffff0000u), m, a[3]);
    a[4] = fmaf(__uint_as_float(v.z << 16),         m, a[4]);
    a[5] = fmaf(__uint_as_float(v.z & 0xffff0000u), m, a[5]);
    a[6] = fmaf(__uint_as_float(v.w << 16),         m, a[6]);
    a[7] = fmaf(__uint_as_float(v.w & 0xffff0000u), m, a[7]);
}

template<int EMIT>
__global__ __launch_bounds__(256) void fused_layer(const ushort* __restrict__ hb,
                                                   const int* __restrict__ offs,
                                                   const int* __restrict__ srt,
                                                   const float* __restrict__ W1,
                                                   const float* __restrict__ b1,
                                                   float* __restrict__ out,
                                                   ushort* __restrict__ outb) {
    __shared__ __align__(16) float rbA[4][64];
    __shared__ __align__(16) float rbB[4][64];
    const int tid  = threadIdx.x;
    const int lane = tid & 63;
    const int wid  = tid >> 6;
    const int g8   = lane >> 3;          // edge slot 0..7
    const int sub8 = lane & 7;           // uint4 (8 bf16) within the row
    const uint roff = (uint)sub8 << 4;   // byte offset within 128-B row
    const int gw   = blockIdx.x * 4 + wid;
    const int GW   = NBLK * 4;
    const char* hbase = (const char*)hb;

    const float4* wrow = (const float4*)(W1 + lane * D);
    const float bj = b1[lane];

    for (int p = gw; p < (N_NODES >> 1); p += GW) {
        const int nA = p << 1;
        const int2 o2 = *(const int2*)(offs + nA);   // begA, endA(=begB)
        const int begA = o2.x;
        const int endA = o2.y;
        const int endB = offs[nA + 2];               // offs[N] sentinel = N_EDGES
        const int emA = (endA > begA) ? endA - 1 : begA;  // deg-0 safe (srt zero-padded)
        const int emB = (endB > endA) ? endB - 1 : endA;

        float aA[8] = {0.f, 0.f, 0.f, 0.f, 0.f, 0.f, 0.f, 0.f};
        float aB[8] = {0.f, 0.f, 0.f, 0.f, 0.f, 0.f, 0.f, 0.f};

        int ebA = begA, ebB = endA;
        while (ebA < endA || ebB < endB) {
            const int eA0 = ebA + g8, eA1 = eA0 + 8;
            const int eB0 = ebB + g8, eB1 = eB0 + 8;
            const int cA0 = min(eA0, emA), cA1 = min(eA1, emA);
            const int cB0 = min(eB0, emB), cB1 = min(eB1, emB);
            const int sA0 = srt[cA0];
            const int sA1 = srt[cA1];
            const int sB0 = srt[cB0];
            const int sB1 = srt[cB1];
            const uint4 vA0 = *(const uint4*)(hbase + (((uint)sA0 << 7) + roff));
            const uint4 vA1 = *(const uint4*)(hbase + (((uint)sA1 << 7) + roff));
            const uint4 vB0 = *(const uint4*)(hbase + (((uint)sB0 << 7) + roff));
            const uint4 vB1 = *(const uint4*)(hbase + (((uint)sB1 << 7) + roff));
            const float mA0 = (eA0 < endA) ? 1.f : 0.f;
            const float mA1 = (eA1 < endA) ? 1.f : 0.f;
            const float mB0 = (eB0 < endB) ? 1.f : 0.f;
            const float mB1 = (eB1 < endB) ? 1.f : 0.f;
            uacc(vA0, mA0, aA);
            uacc(vA1, mA1, aA);
            uacc(vB0, mB0, aB);
            uacc(vB1, mB1, aB);
            ebA += 16; ebB += 16;
        }

        // butterfly over the 8 slot-groups (xor 8/16/32): every lane ends with
        // the full segment sum for its sub8 slice.
#pragma unroll
        for (int j = 0; j < 8; ++j) {
            aA[j] += __shfl_xor(aA[j], 8);
            aA[j] += __shfl_xor(aA[j], 16);
            aA[j] += __shfl_xor(aA[j], 32);
            aB[j] += __shfl_xor(aB[j], 8);
            aB[j] += __shfl_xor(aB[j], 16);
            aB[j] += __shfl_xor(aB[j], 32);
        }

        if (g8 == 0) {       // lanes 0..7: write node A row slices
            float4 t0; t0.x = aA[0]; t0.y = aA[1]; t0.z = aA[2]; t0.w = aA[3];
            float4 t1; t1.x = aA[4]; t1.y = aA[5]; t1.z = aA[6]; t1.w = aA[7];
            ((float4*)rbA[wid])[sub8 * 2]     = t0;
            ((float4*)rbA[wid])[sub8 * 2 + 1] = t1;
        }
        if (g8 == 1) {       // lanes 8..15: write node B row slices
            float4 t0; t0.x = aB[0]; t0.y = aB[1]; t0.z = aB[2]; t0.w = aB[3];
            float4 t1; t1.x = aB[4]; t1.y = aB[5]; t1.z = aB[6]; t1.w = aB[7];
            ((float4*)rbB[wid])[sub8 * 2]     = t0;
            ((float4*)rbB[wid])[sub8 * 2 + 1] = t1;
        }
        // wave-internal LDS RAW: compiler inserts lgkmcnt wait; no barrier needed

        float oA = bj, oB = bj;
        const float4* ra = (const float4*)rbA[wid];
        const float4* rb = (const float4*)rbB[wid];
#pragma unroll
        for (int k4 = 0; k4 < 16; ++k4) {
            const float4 w  = wrow[k4];          // L1-resident (16KB), per-lane row
            const float4 rA = ra[k4];            // LDS broadcast, conflict-free
            const float4 rB = rb[k4];
            oA += rA.x * w.x + rA.y * w.y + rA.z * w.z + rA.w * w.w;
            oB += rB.x * w.x + rB.y * w.y + rB.z * w.z + rB.w * w.w;
        }
        __builtin_nontemporal_store(oA, out + (ll)nA * D + lane);
        __builtin_nontemporal_store(oB, out + (ll)(nA + 1) * D + lane);
        if (EMIT) {
            outb[(ll)nA * D + lane]       = f2bf(oA);   // plain store: keep L2-hot
            outb[(ll)(nA + 1) * D + lane] = f2bf(oB);
        }
    }
}

extern "C" void kernel_launch(void* const* d_in, const int* in_sizes, int n_in,
                              void* d_out, int out_size, void* d_ws, size_t ws_size,
                              hipStream_t stream) {
    const float* x  = (const float*)d_in[0];   // [N, D]
    const int* edge = (const int*)d_in[1];     // [2, E]: src row then dst row
    const float* W1 = (const float*)d_in[2];   // [D, D]
    const float* b1 = (const float*)d_in[3];   // [D]

    const int* src = edge;
    const int* dst = edge + N_EDGES;

    float* out = (float*)d_out;                    // output 0: [N, D]
    float* hid = (float*)d_out + (ll)N_NODES * D;  // output 1: [N, D]

    // xb (bf16 copy of x) lives in the `out` region of d_out: it is only read
    // during layer 1 (which writes hid), and layer 2 overwrites every element.
    ushort* xb = (ushort*)d_out;

    // workspace layout (~24.7 MiB; 25.6 MB proven available)
    char* ws = (char*)d_ws;
    int* cursor   = (int*)ws;  ws += 1024;                                       // [196]
    int* offs     = (int*)ws;  ws += ((size_t)(N_NODES + 1) * 4 + 255) & ~255ull;// [N+1]
    int* srt      = (int*)ws;  ws += ((size_t)(N_EDGES + 8) * 4 + 255) & ~255ull;// [E+8]
    ushort* hidb  = (ushort*)ws; ws += (size_t)N_NODES * D * 2;                  // [N,D] bf16
    int* tmp      = (int*)ws;                                                    // [196*CAP]

    // ---- build CSR via two-pass bucket sort (once; reused by both layers) ----
    init_kernel<<<1, 256, 0, stream>>>(cursor, srt, offs);
    bucketA_kernel<<<PA_BLOCKS, 512, 0, stream>>>(src, dst, cursor, tmp);
    bucketB_kernel<<<BUCKETS, 512, 0, stream>>>(cursor, tmp, srt, offs);

    // ---- bf16 copy of x ----
    cvt_kernel<<<2048, 256, 0, stream>>>(x, xb);

    // ---- layer 1: hid = segsum(x) @ W1^T + b1 (bf16 gather; emits bf16 hid) ----
    fused_layer<1><<<NBLK, 256, 0, stream>>>(xb, offs, srt, W1, b1, hid, hidb);
    // ---- layer 2: out = segsum(hid) @ W1^T + b1 (bf16 gather) ----
    fused_layer<0><<<NBLK, 256, 0, stream>>>(hidb, offs, srt, W1, b1, out, (ushort*)nullptr);
}

// Round 6
// 230.425 us; speedup vs baseline: 1.9203x; 1.0737x over previous
//
#include <hip/hip_runtime.h>

#define N_NODES 100000
#define N_EDGES 1250000
#define D 64

#define BSHIFT 9
#define BUCKETS 196          // ceil(100000 / 512)
#define CAP 8192             // srtTmp capacity per bucket (mean 6378, +22 sigma)
#define CHUNK 4096           // edges per bucketA block
#define PA_BLOCKS ((N_EDGES + CHUNK - 1) / CHUNK)   // 306
#define CVT_BLOCKS 718       // merged-grid blocks doing fp32->bf16 convert
#define LCAP 64              // LDS list capacity per bucket per chunk (mean 21, max<64)

typedef long long ll;
typedef unsigned int uint;

// round-to-nearest-even fp32 -> bf16
__device__ __forceinline__ ushort f2bf(float f) {
    uint u = __float_as_uint(f);
    u += 0x7fffu + ((u >> 16) & 1u);
    return (ushort)(u >> 16);
}

// ---------- init: cursor[b] = b*CAP; zero-pad srt tail; offs[N] sentinel ----------
__global__ void init_kernel(int* __restrict__ cursor, int* __restrict__ srt,
                            int* __restrict__ offs) {
    int t = threadIdx.x;
    if (t < BUCKETS) cursor[t] = t * CAP;
    if (t < 8) srt[N_EDGES + t] = 0;
    if (t == 0) offs[N_NODES] = N_EDGES;
}

// ---------- pass A + cvt in one grid ----------
// Blocks 0..PA_BLOCKS-1: bin edges into 196 coarse buckets (two-phase parallel
// flush). Blocks PA_BLOCKS..: independent fp32->bf16 convert of x (overlapped
// here instead of a separate serial dispatch).
__global__ __launch_bounds__(512) void bucketA_cvt_kernel(const int* __restrict__ src,
                                                          const int* __restrict__ dst,
                                                          int* __restrict__ cursor,
                                                          int* __restrict__ tmp,
                                                          const float* __restrict__ x,
                                                          ushort* __restrict__ xb) {
    int tid = threadIdx.x;
    if (blockIdx.x >= PA_BLOCKS) {
        const int n4 = N_NODES * D / 4;
        int i = (blockIdx.x - PA_BLOCKS) * 512 + tid;
        const int stride = CVT_BLOCKS * 512;
        for (; i < n4; i += stride) {
            float4 v = ((const float4*)x)[i];
            ushort4 o;
            o.x = f2bf(v.x); o.y = f2bf(v.y); o.z = f2bf(v.z); o.w = f2bf(v.w);
            ((ushort4*)xb)[i] = o;
        }
        return;
    }

    __shared__ int lcnt[BUCKETS];
    __shared__ int gbs[BUCKETS];
    __shared__ int list[BUCKETS * LCAP];   // ~49 KB
    if (tid < BUCKETS) lcnt[tid] = 0;
    __syncthreads();

    int base = blockIdx.x * CHUNK;
    int nE = min(CHUNK, N_EDGES - base);
    for (int i = tid; i < nE; i += 512) {
        int e = base + i;
        int s = src[e], d = dst[e];
        int b = d >> BSHIFT;
        int p = atomicAdd(&lcnt[b], 1);            // LDS atomic, cheap
        list[b * LCAP + p] = s | ((d & 511) << 17); // src:17b, dstLow:9b
    }
    __syncthreads();

    if (tid < BUCKETS) gbs[tid] = atomicAdd(&cursor[tid], lcnt[tid]);  // parallel
    __syncthreads();

    int wv = tid >> 6, lane = tid & 63;
    for (int b = wv; b < BUCKETS; b += 8) {        // 8 waves, fire-and-forget stores
        int c = lcnt[b];
        if (lane < c) tmp[gbs[b] + lane] = list[b * LCAP + lane];
    }
}

// ---------- pass B: per-bucket local sort -> final srt + offs ----------
// Scans are wave-shuffle based (4 barriers total instead of ~34).
__global__ __launch_bounds__(512) void bucketB_kernel(const int* __restrict__ cursor,
                                                      const int* __restrict__ tmp,
                                                      int* __restrict__ srt,
                                                      int* __restrict__ offs) {
    __shared__ int hist[512];
    __shared__ int cur[512];
    __shared__ int sbase[256];
    __shared__ int wsum[8];
    const int b = blockIdx.x, tid = threadIdx.x;
    const int wv = tid >> 6, lane = tid & 63;
    const int cbase = b * CAP;
    const int cnt = cursor[b] - cbase;

    hist[tid] = 0;
    // wave 0: exclusive scan over the 196 bucket counts (4 buckets/lane + shfl)
    if (wv == 0) {
        int c0, c1, c2, c3;
        const int b4 = lane << 2;
        c0 = (b4     < BUCKETS) ? (cursor[b4]     - (b4    ) * CAP) : 0;
        c1 = (b4 + 1 < BUCKETS) ? (cursor[b4 + 1] - (b4 + 1) * CAP) : 0;
        c2 = (b4 + 2 < BUCKETS) ? (cursor[b4 + 2] - (b4 + 2) * CAP) : 0;
        c3 = (b4 + 3 < BUCKETS) ? (cursor[b4 + 3] - (b4 + 3) * CAP) : 0;
        const int s1 = c0 + c1, sum = s1 + c2 + c3;
        int run = sum;
#pragma unroll
        for (int d = 1; d < 64; d <<= 1) {
            int t = __shfl_up(run, d);
            if (lane >= d) run += t;
        }
        const int lex = run - sum;        // exclusive prefix of this lane's group
        sbase[b4]     = lex;
        sbase[b4 + 1] = lex + c0;
        sbase[b4 + 2] = lex + s1;
        sbase[b4 + 3] = lex + s1 + c2;
    }
    __syncthreads();
    const int gbase = sbase[b];

    for (int i = tid; i < cnt; i += 512) {
        int ln = tmp[cbase + i] >> 17;
        atomicAdd(&hist[ln], 1);          // LDS atomic, avg 12.5/node
    }
    __syncthreads();

    // 512-wide exclusive scan: per-wave shfl inclusive scan + wave-offset add
    const int x = hist[tid];
    int v = x;
#pragma unroll
    for (int d = 1; d < 64; d <<= 1) {
        int t = __shfl_up(v, d);
        if (lane >= d) v += t;
    }
    if (lane == 63) wsum[wv] = v;
    __syncthreads();
    int woff = 0;
#pragma unroll
    for (int k = 0; k < 8; ++k) woff += (k < wv) ? wsum[k] : 0;   // LDS broadcasts
    const int excl = v + woff - x;
    cur[tid] = excl;

    const int node0 = b << BSHIFT;
    const int nloc = min(512, N_NODES - node0);
    if (tid < nloc) offs[node0 + tid] = gbase + excl;   // coalesced
    __syncthreads();

    for (int i = tid; i < cnt; i += 512) {
        int t = tmp[cbase + i];            // L2-hot (second read)
        int ln = t >> 17;
        int p = atomicAdd(&cur[ln], 1);
        srt[gbase + p] = t & 0x1FFFF;      // random within 25KB window, L2-buffered
    }
}

// ---------- fused pull + linear: bf16 uint2 gather, node-pair, 8 in flight ----------
// R2 geometry (best measured 70.8us/layer) minus the Wreg[16] register hog:
// the epilogue reads W rows from L1 (16KB, resident) per use. 32-bit voffset
// addressing (base + (idx<<7) + (sub<<3)). Goal: VGPR<=64 -> 8 waves/SIMD cap.
// NO min-waves launch bound (R4: forcing -> spills).
#define NBLK 2048
#define ACC4(P, M, AX, AY, AZ, AW)                        \
    {                                                     \
        float f0 = __uint_as_float((P).x << 16);          \
        float f1 = __uint_as_float((P).x & 0xffff0000u);  \
        float f2 = __uint_as_float((P).y << 16);          \
        float f3 = __uint_as_float((P).y & 0xffff0000u);  \
        AX = fmaf(f0, (M), AX); AY = fmaf(f1, (M), AY);   \
        AZ = fmaf(f2, (M), AZ); AW = fmaf(f3, (M), AW);   \
    }

template<int EMIT>
__global__ __launch_bounds__(256) void fused_layer(const ushort* __restrict__ hb,
                                                   const int* __restrict__ offs,
                                                   const int* __restrict__ srt,
                                                   const float* __restrict__ W1,
                                                   const float* __restrict__ b1,
                                                   float* __restrict__ out,
                                                   ushort* __restrict__ outb) {
    __shared__ __align__(16) float rbA[4][64];
    __shared__ __align__(16) float rbB[4][64];
    const int tid  = threadIdx.x;
    const int lane = tid & 63;
    const int wid  = tid >> 6;
    const int g    = lane >> 4;          // edge slot group 0..3
    const int sub  = lane & 15;          // uint2 (4 bf16) within the row
    const uint roff = (uint)sub << 3;    // byte offset within 128-B row
    const int gw   = blockIdx.x * 4 + wid;
    const int GW   = NBLK * 4;
    const int goff = g << 2;
    const char* hbase = (const char*)hb;

    const float4* wrow = (const float4*)(W1 + lane * D);
    const float bj = b1[lane];

    for (int p = gw; p < (N_NODES >> 1); p += GW) {
        const int nA = p << 1;
        const int2 o2 = *(const int2*)(offs + nA);   // begA, endA(=begB)
        const int begA = o2.x;
        const int endA = o2.y;
        const int endB = offs[nA + 2];               // offs[N] sentinel = N_EDGES
        const int emA = (endA > begA) ? endA - 1 : begA;  // deg-0 safe (srt zero-padded)
        const int emB = (endB > endA) ? endB - 1 : endA;

        float aAx = 0.f, aAy = 0.f, aAz = 0.f, aAw = 0.f;
        float aBx = 0.f, aBy = 0.f, aBz = 0.f, aBw = 0.f;

        int ebA = begA, ebB = endA;
        while (ebA < endA || ebB < endB) {
            const int eA = ebA + goff;
            const int eB = ebB + goff;
            const int cA0 = min(eA,     emA), cA1 = min(eA + 1, emA);
            const int cA2 = min(eA + 2, emA), cA3 = min(eA + 3, emA);
            const int cB0 = min(eB,     emB), cB1 = min(eB + 1, emB);
            const int cB2 = min(eB + 2, emB), cB3 = min(eB + 3, emB);
            const int sA0 = srt[cA0];
            const int sA1 = srt[cA1];
            const int sA2 = srt[cA2];
            const int sA3 = srt[cA3];
            const int sB0 = srt[cB0];
            const int sB1 = srt[cB1];
            const int sB2 = srt[cB2];
            const int sB3 = srt[cB3];
            const uint2 vA0 = *(const uint2*)(hbase + (((uint)sA0 << 7) + roff));
            const uint2 vA1 = *(const uint2*)(hbase + (((uint)sA1 << 7) + roff));
            const uint2 vA2 = *(const uint2*)(hbase + (((uint)sA2 << 7) + roff));
            const uint2 vA3 = *(const uint2*)(hbase + (((uint)sA3 << 7) + roff));
            const uint2 vB0 = *(const uint2*)(hbase + (((uint)sB0 << 7) + roff));
            const uint2 vB1 = *(const uint2*)(hbase + (((uint)sB1 << 7) + roff));
            const uint2 vB2 = *(const uint2*)(hbase + (((uint)sB2 << 7) + roff));
            const uint2 vB3 = *(const uint2*)(hbase + (((uint)sB3 << 7) + roff));
            const float mA0 = (eA     < endA) ? 1.f : 0.f;
            const float mA1 = (eA + 1 < endA) ? 1.f : 0.f;
            const float mA2 = (eA + 2 < endA) ? 1.f : 0.f;
            const float mA3 = (eA + 3 < endA) ? 1.f : 0.f;
            const float mB0 = (eB     < endB) ? 1.f : 0.f;
            const float mB1 = (eB + 1 < endB) ? 1.f : 0.f;
            const float mB2 = (eB + 2 < endB) ? 1.f : 0.f;
            const float mB3 = (eB + 3 < endB) ? 1.f : 0.f;
            ACC4(vA0, mA0, aAx, aAy, aAz, aAw);
            ACC4(vA1, mA1, aAx, aAy, aAz, aAw);
            ACC4(vA2, mA2, aAx, aAy, aAz, aAw);
            ACC4(vA3, mA3, aAx, aAy, aAz, aAw);
            ACC4(vB0, mB0, aBx, aBy, aBz, aBw);
            ACC4(vB1, mB1, aBx, aBy, aBz, aBw);
            ACC4(vB2, mB2, aBx, aBy, aBz, aBw);
            ACC4(vB3, mB3, aBx, aBy, aBz, aBw);
            ebA += 16; ebB += 16;
        }

        // cross-group reduce: after xor16+xor32 every lane holds the full sum
        aAx += __shfl_xor(aAx, 16); aAy += __shfl_xor(aAy, 16);
        aAz += __shfl_xor(aAz, 16); aAw += __shfl_xor(aAw, 16);
        aBx += __shfl_xor(aBx, 16); aBy += __shfl_xor(aBy, 16);
        aBz += __shfl_xor(aBz, 16); aBw += __shfl_xor(aBw, 16);
        aAx += __shfl_xor(aAx, 32); aAy += __shfl_xor(aAy, 32);
        aAz += __shfl_xor(aAz, 32); aAw += __shfl_xor(aAw, 32);
        aBx += __shfl_xor(aBx, 32); aBy += __shfl_xor(aBy, 32);
        aBz += __shfl_xor(aBz, 32); aBw += __shfl_xor(aBw, 32);

        if (g == 0) {
            float4 t; t.x = aAx; t.y = aAy; t.z = aAz; t.w = aAw;
            *((float4*)rbA[wid] + sub) = t;     // lanes 0-15 consecutive: conflict-free
        }
        if (g == 1) {
            float4 t; t.x = aBx; t.y = aBy; t.z = aBz; t.w = aBw;
            *((float4*)rbB[wid] + sub) = t;
        }
        // wave-internal LDS RAW: compiler inserts lgkmcnt wait; no barrier needed

        float oA = bj, oB = bj;
        const float4* ra = (const float4*)rbA[wid];
        const float4* rb = (const float4*)rbB[wid];
#pragma unroll
        for (int k4 = 0; k4 < 16; ++k4) {
            const float4 w  = wrow[k4];          // L1-resident (16KB), per-lane row
            const float4 rA = ra[k4];            // LDS broadcast, conflict-free
            const float4 rB = rb[k4];
            oA += rA.x * w.x + rA.y * w.y + rA.z * w.z + rA.w * w.w;
            oB += rB.x * w.x + rB.y * w.y + rB.z * w.z + rB.w * w.w;
        }
        __builtin_nontemporal_store(oA, out + (ll)nA * D + lane);
        __builtin_nontemporal_store(oB, out + (ll)(nA + 1) * D + lane);
        if (EMIT) {
            outb[(ll)nA * D + lane]       = f2bf(oA);   // plain store: keep L2-hot
            outb[(ll)(nA + 1) * D + lane] = f2bf(oB);
        }
    }
}

extern "C" void kernel_launch(void* const* d_in, const int* in_sizes, int n_in,
                              void* d_out, int out_size, void* d_ws, size_t ws_size,
                              hipStream_t stream) {
    const float* x  = (const float*)d_in[0];   // [N, D]
    const int* edge = (const int*)d_in[1];     // [2, E]: src row then dst row
    const float* W1 = (const float*)d_in[2];   // [D, D]
    const float* b1 = (const float*)d_in[3];   // [D]

    const int* src = edge;
    const int* dst = edge + N_EDGES;

    float* out = (float*)d_out;                    // output 0: [N, D]
    float* hid = (float*)d_out + (ll)N_NODES * D;  // output 1: [N, D]

    // xb (bf16 copy of x) lives in the `out` region of d_out: it is only read
    // during layer 1 (which writes hid), and layer 2 overwrites every element.
    ushort* xb = (ushort*)d_out;

    // workspace layout (~24.7 MiB; 25.6 MB proven available)
    char* ws = (char*)d_ws;
    int* cursor   = (int*)ws;  ws += 1024;                                       // [196]
    int* offs     = (int*)ws;  ws += ((size_t)(N_NODES + 1) * 4 + 255) & ~255ull;// [N+1]
    int* srt      = (int*)ws;  ws += ((size_t)(N_EDGES + 8) * 4 + 255) & ~255ull;// [E+8]
    ushort* hidb  = (ushort*)ws; ws += (size_t)N_NODES * D * 2;                  // [N,D] bf16
    int* tmp      = (int*)ws;                                                    // [196*CAP]

    // ---- build CSR (bucket sort) with cvt overlapped in the same grid ----
    init_kernel<<<1, 256, 0, stream>>>(cursor, srt, offs);
    bucketA_cvt_kernel<<<PA_BLOCKS + CVT_BLOCKS, 512, 0, stream>>>(src, dst, cursor,
                                                                   tmp, x, xb);
    bucketB_kernel<<<BUCKETS, 512, 0, stream>>>(cursor, tmp, srt, offs);

    // ---- layer 1: hid = segsum(x) @ W1^T + b1 (bf16 gather; emits bf16 hid) ----
    fused_layer<1><<<NBLK, 256, 0, stream>>>(xb, offs, srt, W1, b1, hid, hidb);
    // ---- layer 2: out = segsum(hid) @ W1^T + b1 (bf16 gather) ----
    fused_layer<0><<<NBLK, 256, 0, stream>>>(hidb, offs, srt, W1, b1, out, (ushort*)nullptr);
}